// Round 2
// baseline (3281.401 us; speedup 1.0000x reference)
//
#include <hip/hip_runtime.h>

#define DEV __device__ __forceinline__

typedef unsigned short u16;
typedef unsigned int   u32;
typedef float f32x4 __attribute__((ext_vector_type(4)));
typedef __bf16 bf16x8 __attribute__((ext_vector_type(8)));

static constexpr float BNS = 0.9999950000374997f; // 1/sqrt(1+1e-5)

DEV float b2f(u32 s){ union{u32 i; float f;} c; c.i = s<<16; return c.f; }
DEV u16   f2b(float x){ union{float f; u32 i;} c; c.f=x; u32 r=c.i + 0x7fffu + ((c.i>>16)&1u); return (u16)(r>>16); }
DEV float leaky(float x){ return x>0.f ? x : 0.2f*x; }
DEV float wredsum(float v){
  #pragma unroll
  for(int d=32; d; d>>=1) v += __shfl_xor(v, d);
  return v;
}
DEV void gl16(const void* g, void* l){
  __builtin_amdgcn_global_load_lds((const __attribute__((address_space(1))) u32*)g,
                                   (__attribute__((address_space(3))) u32*)l, 16, 0, 0);
}

// ---------- prep: (B,3,N) f32 -> (B,N,4) f32 (pad 0) ----------
__global__ __launch_bounds__(256) void k_prep(const float* __restrict__ x, float* __restrict__ X0){
  int i = blockIdx.x*256 + threadIdx.x;          // b*N+n, 32768
  int b = i>>11, n = i&2047;
  const float* xb = x + ((size_t)b*3)*2048 + n;
  f32x4 v; v.x=xb[0]; v.y=xb[2048]; v.z=xb[4096]; v.w=0.f;
  ((f32x4*)X0)[i] = v;
}

// ---------- pack W1 (64,6) f32 -> (64,32) f32 matching padded H1 layout ----------
__global__ __launch_bounds__(256) void k_packw1(const float* __restrict__ W1, float* __restrict__ Wp){
  for(int u=threadIdx.x; u<2048; u+=256){
    int o=u>>5, c=u&31;
    float val=0.f;
    if(c<3)            val = W1[o*6+c];
    else if(c>=4&&c<7) val = W1[o*6+3+(c-4)];
    Wp[u]=val;
  }
}

// ---------- pack f32 weight -> bf16 ----------
__global__ __launch_bounds__(256) void k_w2b(const float* __restrict__ W, u16* __restrict__ Wb, int n){
  int i = blockIdx.x*256 + threadIdx.x;
  if(i<n) Wb[i]=f2b(W[i]);
}

// ---------- squared norms ----------
template<int CP>
__global__ __launch_bounds__(256) void k_sqnorm(const float* __restrict__ X, float* __restrict__ xx){
  int i = blockIdx.x*256 + threadIdx.x;
  const f32x4* p = (const f32x4*)(X + (size_t)i*CP);
  f32x4 a4 = {0.f,0.f,0.f,0.f};
  #pragma unroll
  for(int c=0;c<CP/4;c++){ f32x4 v=p[c]; a4 += v*v; }
  xx[i] = (a4.x+a4.y)+(a4.z+a4.w);
}

// ---------- fused pd + top-20 (self excluded by index), 4-way column split ----------
template<int CP,int TM>
__global__ __launch_bounds__(256) void k_topk(const float* __restrict__ X, const float* __restrict__ xxg,
                                              float* __restrict__ pv, int* __restrict__ pid){
  __shared__ __align__(16) float tile[TM*CP];
  __shared__ float txx[TM];
  const int b = blockIdx.y, z = blockIdx.z;
  const int n = (blockIdx.x<<8) + threadIdx.x;
  const float* Xb = X + (((size_t)b)<<11)*CP;
  f32x4 q4[CP/4];
  {
    const f32x4* qp = (const f32x4*)(Xb + (size_t)n*CP);
    #pragma unroll
    for(int c=0;c<CP/4;c++) q4[c]=qp[c];
  }
  float v[20]; int id[20];
  #pragma unroll
  for(int j=0;j<20;j++){ v[j]=-3.4e38f; id[j]=0; }
  const int mbase = z*512;
  for(int t0=0;t0<512;t0+=TM){
    __syncthreads();
    {
      const f32x4* src = (const f32x4*)(Xb + (size_t)(mbase+t0)*CP);
      f32x4* dst = (f32x4*)tile;
      for(int u=threadIdx.x; u<TM*CP/4; u+=256) dst[u]=src[u];
      for(int u=threadIdx.x; u<TM; u+=256) txx[u]=xxg[(((size_t)b)<<11)+mbase+t0+u];
    }
    __syncthreads();
    for(int mm=0;mm<TM;mm++){
      const f32x4* kp = (const f32x4*)(tile + mm*CP);
      f32x4 a4 = {0.f,0.f,0.f,0.f};
      #pragma unroll
      for(int c=0;c<CP/4;c++) a4 += kp[c]*q4[c];
      float d = (a4.x+a4.y)+(a4.z+a4.w);
      const int m = mbase + t0 + mm;
      float p = d + d - txx[mm];          // rank-equivalent to pd (row-constant omitted)
      p = (m==n) ? -3.4e38f : p;          // exclude self
      if(p > v[19]){
        #pragma unroll
        for(int j=19;j>=1;--j){
          bool sh = p > v[j-1];
          bool at = p > v[j];
          v[j]  = sh ? v[j-1]  : (at ? p : v[j]);
          id[j] = sh ? id[j-1] : (at ? m : id[j]);
        }
        if(p > v[0]){ v[0]=p; id[0]=m; }
      }
    }
  }
  const size_t row = ((((size_t)b)<<11)+n)*4 + z;
  float* pvp = pv + row*20; int* pip = pid + row*20;
  #pragma unroll
  for(int j=0;j<20;j++){ pvp[j]=v[j]; pip[j]=id[j]; }
}

// ---------- merge 4 partial lists -> knn (20) ----------
__global__ __launch_bounds__(256) void k_merge(const float* __restrict__ pv, const int* __restrict__ pid,
                                               int* __restrict__ knn){
  const int i = blockIdx.x*256 + threadIdx.x;
  float v[20]; int id[20];
  #pragma unroll
  for(int j=0;j<20;j++){ v[j]=-3.4e38f; id[j]=0; }
  const float* pvp = pv + (size_t)i*80;
  const int*   pip = pid + (size_t)i*80;
  for(int c=0;c<80;c++){
    float p = pvp[c]; int m = pip[c];
    if(p > v[19]){
      #pragma unroll
      for(int j=19;j>=1;--j){
        bool sh = p > v[j-1];
        bool at = p > v[j];
        v[j]  = sh ? v[j-1]  : (at ? p : v[j]);
        id[j] = sh ? id[j-1] : (at ? m : id[j]);
      }
      if(p > v[0]){ v[0]=p; id[0]=m; }
    }
  }
  int* o = knn + (size_t)i*20;
  #pragma unroll
  for(int j=0;j<20;j++) o[j]=id[j];
}

// ---------- attention: gather + softmax + feat; H = [q, feat] bf16 (B,N,HS) ----------
template<int CP,int HS>
__global__ __launch_bounds__(256) void k_attn(const float* __restrict__ X, const int* __restrict__ knn,
                                              u16* __restrict__ H){
  const int i = blockIdx.x*256 + threadIdx.x;
  const float* Xb = X + (((size_t)(i>>11))<<11)*CP;
  const float* q  = X + (size_t)i*CP;
  int nb[20];
  { const int* kp = knn + (size_t)i*20;
    #pragma unroll
    for(int j=0;j<20;j++) nb[j]=kp[j]; }
  float s[20];
  #pragma unroll
  for(int j=0;j<20;j++) s[j]=0.f;
  constexpr int CH = (CP<32)?CP:32;
  for(int c0=0;c0<CP;c0+=CH){
    f32x4 qc[CH/4];
    #pragma unroll
    for(int c=0;c<CH/4;c++) qc[c]=((const f32x4*)(q+c0))[c];
    #pragma unroll
    for(int j=0;j<20;j++){
      const f32x4* kr = (const f32x4*)(Xb + (size_t)nb[j]*CP + c0);
      float a=0.f;
      #pragma unroll
      for(int c=0;c<CH/4;c++){ f32x4 kv=kr[c]; a += kv.x*qc[c].x + kv.y*qc[c].y + kv.z*qc[c].z + kv.w*qc[c].w; }
      s[j]+=a;
    }
  }
  float mx=s[0];
  #pragma unroll
  for(int j=1;j<20;j++) mx=fmaxf(mx,s[j]);
  float sum=0.f;
  #pragma unroll
  for(int j=0;j<20;j++){ s[j]=__expf(s[j]-mx); sum+=s[j]; }
  float inv=1.f/sum;
  #pragma unroll
  for(int j=0;j<20;j++) s[j]*=inv;
  u16* ho = H + (size_t)i*HS;
  #pragma unroll
  for(int c=0;c<CP;c+=4){
    f32x4 qv = *(const f32x4*)(q+c);
    ushort4 st = {f2b(qv.x),f2b(qv.y),f2b(qv.z),f2b(qv.w)};
    *(ushort4*)(ho+c)=st;
  }
  for(int c0=0;c0<CP;c0+=CH){
    float f[CH];
    #pragma unroll
    for(int c=0;c<CH;c++) f[c]=0.f;
    #pragma unroll
    for(int j=0;j<20;j++){
      const f32x4* kr = (const f32x4*)(Xb + (size_t)nb[j]*CP + c0);
      float w=s[j];
      #pragma unroll
      for(int c=0;c<CH/4;c++){ f32x4 kv=kr[c]; f[4*c]+=w*kv.x; f[4*c+1]+=w*kv.y; f[4*c+2]+=w*kv.z; f[4*c+3]+=w*kv.w; }
    }
    #pragma unroll
    for(int c=0;c<CH;c+=4){
      float q0=q[c0+c], q1=q[c0+c+1], q2v=q[c0+c+2], q3=q[c0+c+3];
      ushort4 st = {f2b(f[c]-q0),f2b(f[c+1]-q1),f2b(f[c+2]-q2v),f2b(f[c+3]-q3)};
      *(ushort4*)(ho+CP+c0+c)=st;
    }
  }
  if constexpr(HS > 2*CP){
    ushort4 zz={0,0,0,0};
    #pragma unroll
    for(int c=2*CP;c<HS;c+=4) *(ushort4*)(ho+c)=zz;
  }
}

// ---------- vector conv (O=64): H(B,N,K) bf16 x W(64,K) f32 -> X f32 + Hcat bf16 ----------
template<int K>
__global__ __launch_bounds__(256) void k_vconv(const u16* __restrict__ H, const float* __restrict__ Wg,
                                               const float* __restrict__ g, const float* __restrict__ bb,
                                               float* __restrict__ Xout, u16* __restrict__ Hc, int hoff){
  __shared__ __align__(16) float Ws[K*64];   // [k][o]
  for(int u=threadIdx.x; u<K*64; u+=256){
    int o=u&63, kk=u>>6;
    Ws[u]=Wg[o*K+kk];
  }
  __syncthreads();
  const int gi = blockIdx.x*256 + threadIdx.x;
  const int i = gi>>2, oc = gi&3;
  const u16* hr = H + (size_t)i*K;
  float acc[16];
  #pragma unroll
  for(int o=0;o<16;o++) acc[o]=0.f;
  for(int k0=0;k0<K;k0+=8){
    uint4 hv = *(const uint4*)(hr+k0);
    float hh[8];
    hh[0]=b2f(hv.x&0xffff); hh[1]=b2f(hv.x>>16);
    hh[2]=b2f(hv.y&0xffff); hh[3]=b2f(hv.y>>16);
    hh[4]=b2f(hv.z&0xffff); hh[5]=b2f(hv.z>>16);
    hh[6]=b2f(hv.w&0xffff); hh[7]=b2f(hv.w>>16);
    #pragma unroll
    for(int kk=0;kk<8;kk++){
      const f32x4* wr = (const f32x4*)(Ws + (k0+kk)*64 + oc*16);
      #pragma unroll
      for(int o4=0;o4<4;o4++){
        f32x4 w = wr[o4];
        acc[o4*4]  +=hh[kk]*w.x; acc[o4*4+1]+=hh[kk]*w.y;
        acc[o4*4+2]+=hh[kk]*w.z; acc[o4*4+3]+=hh[kk]*w.w;
      }
    }
  }
  const int ob = oc*16;
  #pragma unroll
  for(int o=0;o<16;o++) acc[o]=leaky(acc[o]*(BNS*g[ob+o])+bb[ob+o]);
  float* xo = Xout + (size_t)i*64 + ob;
  #pragma unroll
  for(int o=0;o<16;o+=4){ f32x4 sv={acc[o],acc[o+1],acc[o+2],acc[o+3]}; *(f32x4*)(xo+o)=sv; }
  u16* hc = Hc + (size_t)i*512 + hoff + ob;
  #pragma unroll
  for(int o=0;o<16;o+=4){ ushort4 st={f2b(acc[o]),f2b(acc[o+1]),f2b(acc[o+2]),f2b(acc[o+3])}; *(ushort4*)(hc+o)=st; }
}

// ---------- MFMA conv: 128x128 tile, BK=32, global_load_lds staging ----------
template<int K,int OSTR,bool OUT32,int HCS>
__global__ __launch_bounds__(256) void k_cmfma(const u16* __restrict__ Wg, const u16* __restrict__ Hin,
                                               const float* __restrict__ g, const float* __restrict__ bb,
                                               float* __restrict__ Xout, u16* __restrict__ Hc, int hoff){
  __shared__ __align__(16) u16 As[128*32];
  __shared__ __align__(16) u16 Bs[128*32];
  const int tid=threadIdx.x, b=blockIdx.z;
  const int n0=blockIdx.x<<7, o0=blockIdx.y<<7;
  const int wid=tid>>6, lane=tid&63, wr=wid>>1, wc=wid&1, lm=lane&15, quad=lane>>4;
  f32x4 acc[4][4];
  #pragma unroll
  for(int a=0;a<4;a++)
    #pragma unroll
    for(int c=0;c<4;c++) acc[a][c]=(f32x4){0.f,0.f,0.f,0.f};
  const int r0=tid>>2, kc=(tid&3)<<3;
  const u16* A0 = Wg + (size_t)(o0+r0)*K + kc;
  const u16* A1 = A0 + (size_t)64*K;
  const u16* B0 = Hin + ((size_t)b*2048 + n0 + r0)*K + kc;
  const u16* B1 = B0 + (size_t)64*K;
  u16* Aw = As + wid*512;   // wave-uniform LDS base; HW adds lane*16B
  u16* Bw = Bs + wid*512;
  for(int k0=0;k0<K;k0+=32){
    __syncthreads();
    gl16(A0+k0, Aw);  gl16(A1+k0, Aw+2048);
    gl16(B0+k0, Bw);  gl16(B1+k0, Bw+2048);
    __syncthreads();
    bf16x8 af[4], bfr[4];
    #pragma unroll
    for(int mi=0;mi<4;mi++) af[mi]=*(const bf16x8*)(As + ((wr<<6)+(mi<<4)+lm)*32 + (quad<<3));
    #pragma unroll
    for(int ni=0;ni<4;ni++) bfr[ni]=*(const bf16x8*)(Bs + ((wc<<6)+(ni<<4)+lm)*32 + (quad<<3));
    #pragma unroll
    for(int mi=0;mi<4;mi++)
      #pragma unroll
      for(int ni=0;ni<4;ni++)
        acc[mi][ni]=__builtin_amdgcn_mfma_f32_16x16x32_bf16(af[mi],bfr[ni],acc[mi][ni],0,0,0);
  }
  #pragma unroll
  for(int mi=0;mi<4;mi++){
    const int o = o0 + (wr<<6) + (mi<<4) + (quad<<2);
    float g0=BNS*g[o],  g1v=BNS*g[o+1], g2v=BNS*g[o+2], g3v=BNS*g[o+3];
    float b0=bb[o], b1v=bb[o+1], b2v=bb[o+2], b3v=bb[o+3];
    #pragma unroll
    for(int ni=0;ni<4;ni++){
      const int n = n0 + (wc<<6) + (ni<<4) + lm;
      const size_t pt = (size_t)b*2048 + n;
      f32x4 cc = acc[mi][ni];
      float y0=leaky(cc.x*g0+b0);
      float y1=leaky(cc.y*g1v+b1v);
      float y2=leaky(cc.z*g2v+b2v);
      float y3=leaky(cc.w*g3v+b3v);
      if constexpr(OUT32){
        f32x4 sv={y0,y1,y2,y3};
        *(f32x4*)(Xout + pt*OSTR + o)=sv;
      }
      ushort4 st={f2b(y0),f2b(y1),f2b(y2),f2b(y3)};
      *(ushort4*)(Hc + pt*HCS + hoff + o)=st;
    }
  }
}

// ---------- head: per-point scores = leaky(x5 . Watt^T) ----------
__global__ __launch_bounds__(256) void k_scores(const u16* __restrict__ X5, const float* __restrict__ Watt,
                                                float* __restrict__ S){
  __shared__ __align__(16) f32x4 Wa[1024];
  for(int u=threadIdx.x; u<1024; u+=256){
    f32x4 w; w.x=Watt[u]; w.y=Watt[1024+u]; w.z=Watt[2048+u]; w.w=Watt[3072+u];
    Wa[u]=w;
  }
  __syncthreads();
  const int i = blockIdx.x*256 + threadIdx.x;
  const u16* xr = X5 + (size_t)i*1024;
  f32x4 a={0.f,0.f,0.f,0.f};
  for(int k0=0;k0<1024;k0+=8){
    uint4 hv=*(const uint4*)(xr+k0);
    float hh[8];
    hh[0]=b2f(hv.x&0xffff); hh[1]=b2f(hv.x>>16);
    hh[2]=b2f(hv.y&0xffff); hh[3]=b2f(hv.y>>16);
    hh[4]=b2f(hv.z&0xffff); hh[5]=b2f(hv.z>>16);
    hh[6]=b2f(hv.w&0xffff); hh[7]=b2f(hv.w>>16);
    #pragma unroll
    for(int kk=0;kk<8;kk++){
      f32x4 w=Wa[k0+kk];
      a.x+=hh[kk]*w.x; a.y+=hh[kk]*w.y; a.z+=hh[kk]*w.z; a.w+=hh[kk]*w.w;
    }
  }
  f32x4 sv={leaky(a.x),leaky(a.y),leaky(a.z),leaky(a.w)};
  ((f32x4*)S)[i]=sv;
}

// ---------- head: att[b,h,e] = sum_n x5[b,n,e]*S[b,n,h] (atomic partials) ----------
__global__ __launch_bounds__(256) void k_att(const u16* __restrict__ X5, const float* __restrict__ S,
                                             float* __restrict__ att){
  __shared__ __align__(16) f32x4 Sh[256];
  const int b=blockIdx.z, e=(blockIdx.x<<8)+threadIdx.x, nbase=blockIdx.y<<8;
  Sh[threadIdx.x]=((const f32x4*)S)[(((size_t)b)<<11)+nbase+threadIdx.x];
  __syncthreads();
  f32x4 a={0.f,0.f,0.f,0.f};
  const u16* xp = X5 + ((((size_t)b)<<11)+nbase)*1024 + e;
  for(int nn=0;nn<256;nn++){
    float xv=b2f(xp[(size_t)nn*1024]);
    f32x4 s=Sh[nn];
    a.x+=xv*s.x; a.y+=xv*s.y; a.z+=xv*s.z; a.w+=xv*s.w;
  }
  float* ab = att + (((size_t)b)<<12) + e;
  atomicAdd(ab,      a.x); atomicAdd(ab+1024, a.y);
  atomicAdd(ab+2048, a.z); atomicAdd(ab+3072, a.w);
}

// ---------- head: layernorm + leaky ----------
__global__ __launch_bounds__(256) void k_ln(const float* __restrict__ att, const float* __restrict__ lg,
                                            const float* __restrict__ lb, float* __restrict__ L){
  const int b=blockIdx.x, t=threadIdx.x;
  const float* a = att + (((size_t)b)<<12);
  float s=0.f, sq=0.f;
  for(int u=t;u<4096;u+=256){ float x=a[u]; s+=x; sq+=x*x; }
  s=wredsum(s); sq=wredsum(sq);
  __shared__ float rs[4], rq[4];
  const int wid=t>>6, lane=t&63;
  if(lane==0){ rs[wid]=s; rq[wid]=sq; }
  __syncthreads();
  s=rs[0]+rs[1]+rs[2]+rs[3];
  sq=rq[0]+rq[1]+rq[2]+rq[3];
  const float mean=s*(1.f/4096.f);
  const float var=sq*(1.f/4096.f)-mean*mean;
  const float rstd=rsqrtf(var+1e-5f);
  float* Lb = L + (((size_t)b)<<12);
  for(int u=t;u<4096;u+=256){
    float x=(a[u]-mean)*rstd*lg[u]+lb[u];
    Lb[u]=leaky(x);
  }
}

// ---------- head: FC (wave-per-output), all-f32 ----------
template<int IN,int OUT,int MODE>   // MODE 0: bn+leaky -> f32 ; 2: plain -> f32 out
__global__ __launch_bounds__(256) void k_fc(const float* __restrict__ Xin, const float* __restrict__ Wg,
                                            const float* __restrict__ bias, const float* __restrict__ g,
                                            const float* __restrict__ bb, float* __restrict__ out){
  const int gw=(blockIdx.x<<2)+(threadIdx.x>>6);
  const int lane=threadIdx.x&63;
  const int o=gw%OUT, b=gw/OUT;
  constexpr int CHL=IN/64;
  const float* xr = Xin + (size_t)b*IN + lane*CHL;
  const float* wr = Wg  + (size_t)o*IN + lane*CHL;
  float a=0.f;
  #pragma unroll
  for(int c=0;c<CHL;c+=4){
    f32x4 wv=*(const f32x4*)(wr+c);
    f32x4 xv=*(const f32x4*)(xr+c);
    a+=xv.x*wv.x + xv.y*wv.y + xv.z*wv.z + xv.w*wv.w;
  }
  a=wredsum(a);
  if(lane==0){
    float y=a+bias[o];
    if constexpr(MODE<2){
      y=leaky(y*(BNS*g[o])+bb[o]);
    }
    out[(size_t)b*OUT+o]=y;
  }
}

extern "C" void kernel_launch(void* const* d_in, const int* in_sizes, int n_in,
                              void* d_out, int out_size, void* d_ws, size_t ws_size,
                              hipStream_t stream){
  const float* x  =(const float*)d_in[0];
  const float* W1 =(const float*)d_in[1];
  const float* g1 =(const float*)d_in[2];
  const float* b1 =(const float*)d_in[3];
  const float* W2 =(const float*)d_in[4];
  const float* g2 =(const float*)d_in[5];
  const float* b2 =(const float*)d_in[6];
  const float* W3 =(const float*)d_in[7];
  const float* g3 =(const float*)d_in[8];
  const float* b3 =(const float*)d_in[9];
  const float* W4 =(const float*)d_in[10];
  const float* g4 =(const float*)d_in[11];
  const float* b4 =(const float*)d_in[12];
  const float* W5 =(const float*)d_in[13];
  const float* g5 =(const float*)d_in[14];
  const float* b5 =(const float*)d_in[15];
  const float* Watt=(const float*)d_in[16];
  const float* lng=(const float*)d_in[17];
  const float* lnb=(const float*)d_in[18];
  const float* Wl1=(const float*)d_in[19];
  const float* bl1=(const float*)d_in[20];
  const float* g6 =(const float*)d_in[21];
  const float* b6 =(const float*)d_in[22];
  const float* Wl2=(const float*)d_in[23];
  const float* bl2=(const float*)d_in[24];
  const float* g7 =(const float*)d_in[25];
  const float* b7 =(const float*)d_in[26];
  const float* Wl3=(const float*)d_in[27];
  const float* bl3=(const float*)d_in[28];
  char* ws=(char*)d_ws;
  if(ws_size < (size_t)156590080) return;
  float* X0 =(float*)(ws+0);
  float* X1 =(float*)(ws+524288);
  float* X2 =(float*)(ws+8912896);
  float* X3 =(float*)(ws+17301504);
  u16*   H  =(u16*)  (ws+34078720);
  u16*   Hc =(u16*)  (ws+50855936);
  u16*   X5 =(u16*)  (ws+84410368);      // X5 overlays pv/pid (dead by then)
  float* pv =(float*)(ws+84410368);
  int*   pid=(int*)  (ws+94896128);
  float* xx =(float*)(ws+151519232);
  int*   knn=(int*)  (ws+151650304);
  float* Wp1=(float*)(ws+154271744);
  float* S  =(float*)(ws+154279936);
  float* att=(float*)(ws+154804224);
  float* L  =(float*)(ws+155066368);
  float* y1 =(float*)(ws+155328512);
  float* y2 =(float*)(ws+155361280);
  u16*   Wb3=(u16*)  (ws+155377664);
  u16*   Wb4=(u16*)  (ws+155410432);
  u16*   Wb5=(u16*)  (ws+155541504);

  k_prep  <<<128,256,0,stream>>>(x,X0);
  k_packw1<<<1,  256,0,stream>>>(W1,Wp1);
  k_w2b   <<<64, 256,0,stream>>>(W3,Wb3,16384);
  k_w2b   <<<256,256,0,stream>>>(W4,Wb4,65536);
  k_w2b   <<<2048,256,0,stream>>>(W5,Wb5,524288);
  // layer 1 (C=3 padded to 4)
  k_sqnorm<4>   <<<128,256,0,stream>>>(X0,xx);
  k_topk<4,256> <<<dim3(8,16,4),256,0,stream>>>(X0,xx,pv,pid);
  k_merge       <<<128,256,0,stream>>>(pv,pid,knn);
  k_attn<4,32>  <<<128,256,0,stream>>>(X0,knn,H);
  k_vconv<32>   <<<512,256,0,stream>>>(H,Wp1,g1,b1,X1,Hc,0);
  // layer 2 (C=64)
  k_sqnorm<64>   <<<128,256,0,stream>>>(X1,xx);
  k_topk<64,128> <<<dim3(8,16,4),256,0,stream>>>(X1,xx,pv,pid);
  k_merge        <<<128,256,0,stream>>>(pv,pid,knn);
  k_attn<64,128> <<<128,256,0,stream>>>(X1,knn,H);
  k_vconv<128>   <<<512,256,0,stream>>>(H,W2,g2,b2,X2,Hc,64);
  // layer 3 (C=64 -> O=128)
  k_sqnorm<64>   <<<128,256,0,stream>>>(X2,xx);
  k_topk<64,128> <<<dim3(8,16,4),256,0,stream>>>(X2,xx,pv,pid);
  k_merge        <<<128,256,0,stream>>>(pv,pid,knn);
  k_attn<64,128> <<<128,256,0,stream>>>(X2,knn,H);
  k_cmfma<128,128,true,512> <<<dim3(16,1,16),256,0,stream>>>(Wb3,H,g3,b3,X3,Hc,128);
  // layer 4 (C=128 -> O=256)
  k_sqnorm<128>  <<<128,256,0,stream>>>(X3,xx);
  k_topk<128,64> <<<dim3(8,16,4),256,0,stream>>>(X3,xx,pv,pid);
  k_merge        <<<128,256,0,stream>>>(pv,pid,knn);
  k_attn<128,256><<<128,256,0,stream>>>(X3,knn,H);
  k_cmfma<256,1,false,512> <<<dim3(16,2,16),256,0,stream>>>(Wb4,H,g4,b4,nullptr,Hc,256);
  // conv5 (512 -> 1024)
  k_cmfma<512,1,false,1024><<<dim3(16,8,16),256,0,stream>>>(Wb5,Hc,g5,b5,nullptr,X5,0);
  // head
  k_scores<<<128,256,0,stream>>>(X5,Watt,S);
  hipMemsetAsync(att,0,16*4096*4,stream);
  k_att   <<<dim3(4,8,16),256,0,stream>>>(X5,S,att);
  k_ln    <<<16,256,0,stream>>>(att,lng,lnb,L);
  k_fc<4096,512,0><<<2048,256,0,stream>>>(L, Wl1,bl1,g6,b6,y1);
  k_fc<512,256,0> <<<1024,256,0,stream>>>(y1,Wl2,bl2,g7,b7,y2);
  k_fc<256,40,2>  <<<160, 256,0,stream>>>(y2,Wl3,bl3,nullptr,nullptr,(float*)d_out);
}